// Round 2
// baseline (1708.421 us; speedup 1.0000x reference)
//
#include <hip/hip_runtime.h>
#include <hip/hip_bf16.h>
#include <math.h>

// ---------------- prep: BN folding + weight transposes ----------------
// grid 7169 x 256
__global__ void k_prep(const float* __restrict__ p1_w, const float* __restrict__ p1_b,
                       const float* __restrict__ bn1_g, const float* __restrict__ bn1_b,
                       const float* __restrict__ bn1_m, const float* __restrict__ bn1_v,
                       const float* __restrict__ off_w,
                       const float* __restrict__ dcn_w, const float* __restrict__ dcn_b,
                       const float* __restrict__ bn2_g, const float* __restrict__ bn2_b,
                       const float* __restrict__ bn2_m, const float* __restrict__ bn2_v,
                       float* __restrict__ p1_wT, float* __restrict__ off_wT,
                       float* __restrict__ dcn_wT,
                       float* __restrict__ bias1f, float* __restrict__ inv2f,
                       float* __restrict__ bias2f)
{
    int blk = blockIdx.x, t = threadIdx.x;
    if (blk == 0) {
        float inv1 = bn1_g[t] / sqrtf(bn1_v[t] + 1e-5f);
        bias1f[t] = p1_b[t] * inv1 + bn1_b[t] - bn1_m[t] * inv1;
        float inv2 = bn2_g[t] / sqrtf(bn2_v[t] + 1e-5f);
        inv2f[t] = inv2;
        bias2f[t] = dcn_b[t] * inv2 + bn2_b[t] - bn2_m[t] * inv2;
    } else if (blk <= 256) {
        int ci = blk - 1;
        float inv1 = bn1_g[t] / sqrtf(bn1_v[t] + 1e-5f);
        p1_wT[ci*256 + t] = p1_w[t*256 + ci] * inv1;   // [ci][o], bn1 scale folded
    } else if (blk <= 2560) {
        int ck = blk - 257;                             // ck = c*9+k
        dcn_wT[ck*256 + t] = dcn_w[t*2304 + ck];        // [ck][o]
    } else {
        int kk = blk - 2561;                            // kk = ci*9+tap, 0..4607
        if (t < 32) {
            int tt = (t < 27) ? t : 0;                  // clamp: no speculative OOB
            float v = off_w[tt*4608 + kk];
            off_wT[kk*32 + t] = (t < 27) ? v : 0.f;
        }
    }
}

// ---------------- transpose + flip: featT[b][h][w][c] = feature[b][c][h][63-w] ----
// grid 2048 x 256  (8 b * 64 h * 4 c-groups)
__global__ void k_featT(const float* __restrict__ feature, float* __restrict__ featT)
{
    __shared__ float tile[64][65];
    int bb = blockIdx.x;
    int cg = bb & 3, h = (bb >> 2) & 63, b = bb >> 8;
    int c0 = cg * 64;
    int t = threadIdx.x;
    int lw = t & 63, li = t >> 6;
    #pragma unroll
    for (int j = 0; j < 16; ++j) {
        int cl = j*4 + li;
        tile[cl][63 - lw] = feature[((b*256 + c0 + cl)*64 + h)*64 + lw];
    }
    __syncthreads();
    #pragma unroll
    for (int j = 0; j < 16; ++j) {
        int wl = j*4 + li;
        featT[((b*64 + h)*64 + wl)*256 + c0 + lw] = tile[lw][wl];
    }
}

// ---------------- proj: 1x1 conv + bn1 as GEMM 256 x 32768 x 256 ----------------
// grid 2048 x 256  (4 o-tiles * 512 (b,h) rows)
__global__ void k_proj(const float* __restrict__ feature,
                       const float* __restrict__ p1_wT, const float* __restrict__ bias1f,
                       float* __restrict__ proj)
{
    __shared__ float A[16*64];   // [ci][o]
    __shared__ float Bt[16*64];  // [ci][w]
    int bb = blockIdx.x;
    int ot = bb & 3; int row = bb >> 2;
    int b = row >> 6, h = row & 63;
    int o0 = ot * 64;
    int t = threadIdx.x;
    int to = t & 15, tp = t >> 4;
    int li = t >> 6, lw = t & 63;
    float acc[4][4] = {};
    for (int ci0 = 0; ci0 < 256; ci0 += 16) {
        #pragma unroll
        for (int j = 0; j < 4; ++j) {
            int r = j*4 + li;
            A[r*64 + lw]  = p1_wT[(ci0 + r)*256 + o0 + lw];
            Bt[r*64 + lw] = feature[((b*256 + ci0 + r)*64 + h)*64 + lw];
        }
        __syncthreads();
        #pragma unroll
        for (int kk = 0; kk < 16; ++kk) {
            const float4 av = *(const float4*)&A[kk*64 + to*4];
            const float4 bv = *(const float4*)&Bt[kk*64 + tp*4];
            const float a[4] = {av.x, av.y, av.z, av.w};
            const float bv4[4] = {bv.x, bv.y, bv.z, bv.w};
            #pragma unroll
            for (int i = 0; i < 4; ++i)
                #pragma unroll
                for (int j = 0; j < 4; ++j)
                    acc[i][j] += a[i] * bv4[j];
        }
        __syncthreads();
    }
    #pragma unroll
    for (int i = 0; i < 4; ++i) {
        int o = o0 + to*4 + i;
        float bs = bias1f[o];
        float4 st = { acc[i][0]+bs, acc[i][1]+bs, acc[i][2]+bs, acc[i][3]+bs };
        *(float4*)&proj[((b*256 + o)*64 + h)*64 + tp*4] = st;
    }
}

// ---------------- off: 3x3 conv (concat[flip,proj] 512ch -> 27) as GEMM -------
// grid 512 x 256  ((b,h) rows), oc padded to 32
__global__ void k_off(const float* __restrict__ feature,
                      const float* __restrict__ proj,
                      const float* __restrict__ off_wT, const float* __restrict__ off_b,
                      float* __restrict__ offv)
{
    __shared__ float Wl[36*32];  // [kk][oc]
    __shared__ float Il[36*64];  // [kk][w]
    int bb = blockIdx.x;
    int b = bb >> 6, h = bb & 63;
    int t = threadIdx.x;
    int to = t & 7, tp = t >> 3;   // to: oc/4, tp: w/2
    float acc[4][2] = {};
    for (int kk0 = 0; kk0 < 4608; kk0 += 36) {
        for (int e = t; e < 36*64; e += 256) {
            int kkl = e >> 6, pl = e & 63;
            int kk = kk0 + kkl;
            int ci = kk / 9, tap = kk % 9;
            int y = h + tap/3 - 1;
            int x = pl + tap%3 - 1;
            float v = 0.f;
            if (y >= 0 && y < 64 && x >= 0 && x < 64) {
                if (ci < 256) v = feature[((b*256 + ci)*64 + y)*64 + (63 - x)];
                else          v = proj[((b*256 + (ci-256))*64 + y)*64 + x];
            }
            Il[kkl*64 + pl] = v;
        }
        for (int e = t; e < 36*32; e += 256) {
            Wl[e] = off_wT[kk0*32 + e];
        }
        __syncthreads();
        #pragma unroll
        for (int kk = 0; kk < 36; ++kk) {
            float4 wv = *(const float4*)&Wl[kk*32 + to*4];
            float2 iv = *(const float2*)&Il[kk*64 + tp*2];
            acc[0][0] += wv.x*iv.x; acc[0][1] += wv.x*iv.y;
            acc[1][0] += wv.y*iv.x; acc[1][1] += wv.y*iv.y;
            acc[2][0] += wv.z*iv.x; acc[2][1] += wv.z*iv.y;
            acc[3][0] += wv.w*iv.x; acc[3][1] += wv.w*iv.y;
        }
        __syncthreads();
    }
    #pragma unroll
    for (int i = 0; i < 4; ++i) {
        int oc = to*4 + i;
        if (oc < 27) {
            float ob = off_b[oc];
            int idx = ((b*27 + oc)*64 + h)*64 + tp*2;
            offv[idx]   = acc[i][0] + ob;
            offv[idx+1] = acc[i][1] + ob;
        }
    }
}

// ---------------- deform sample + masked dcn einsum + bn2 + residual + relu ----
// grid 2048 x 256  (4 o-tiles * 512 (b,h) rows); K = 2304 in chunks of 8c x 9k
__global__ void k_dcn(const float* __restrict__ featT,
                      const float* __restrict__ offv,
                      const float* __restrict__ dcn_wT,
                      const float* __restrict__ proj,
                      const float* __restrict__ inv2f, const float* __restrict__ bias2f,
                      float* __restrict__ out)
{
    __shared__ int   c_off[576*4];
    __shared__ float c_w[576*4];
    __shared__ float Gl[72*68];   // [ckl][p] padded
    __shared__ float Wl[72*64];   // [ckl][o]
    int bb = blockIdx.x;
    int ot = bb & 3; int row = bb >> 2;
    int b = row >> 6, h = row & 63;
    int o0 = ot * 64;
    int t = threadIdx.x;

    // corner phase: bilinear coords + (mask*validity*bilinear) weights per (p,k)
    for (int e = t; e < 576; e += 256) {
        int p = e / 9, k = e % 9;
        int base = (b*27)*4096 + h*64 + p;
        float dy = offv[base + k*4096];
        float dx = offv[base + (9+k)*4096];
        float ms = offv[base + (18+k)*4096];
        ms = 1.f / (1.f + expf(-ms));
        float py = (float)h + (float)(k/3 - 1) + dy;
        float px = (float)p + (float)(k%3 - 1) + dx;
        float y0f = floorf(py), x0f = floorf(px);
        float wy = py - y0f, wx = px - x0f;
        int y0 = (int)y0f, x0 = (int)x0f;
        int y1 = y0 + 1, x1 = x0 + 1;
        float vy0 = (y0 >= 0 && y0 < 64) ? 1.f : 0.f;
        float vy1 = (y1 >= 0 && y1 < 64) ? 1.f : 0.f;
        float vx0 = (x0 >= 0 && x0 < 64) ? 1.f : 0.f;
        float vx1 = (x1 >= 0 && x1 < 64) ? 1.f : 0.f;
        int y0c = min(max(y0,0),63), y1c = min(max(y1,0),63);
        int x0c = min(max(x0,0),63), x1c = min(max(x1,0),63);
        c_off[e*4+0] = (y0c*64 + x0c)*256;
        c_off[e*4+1] = (y0c*64 + x1c)*256;
        c_off[e*4+2] = (y1c*64 + x0c)*256;
        c_off[e*4+3] = (y1c*64 + x1c)*256;
        c_w[e*4+0] = ms * (1.f-wy)*(1.f-wx) * vy0*vx0;
        c_w[e*4+1] = ms * (1.f-wy)*wx       * vy0*vx1;
        c_w[e*4+2] = ms * wy*(1.f-wx)       * vy1*vx0;
        c_w[e*4+3] = ms * wy*wx             * vy1*vx1;
    }
    __syncthreads();

    int to = t & 15, tp = t >> 4;
    float acc[4][4] = {};
    const float* fT = featT + b*(64*64*256);
    for (int cc = 0; cc < 32; ++cc) {
        int c0 = cc * 8;
        // build G tile: 72 ck x 64 p  (lanes -> consecutive c for coalesced gather)
        #pragma unroll 2
        for (int i = 0; i < 18; ++i) {
            int e = t + i*256;
            int cl = e & 7, rest = e >> 3;   // rest = p*9+k
            int p = rest / 9, k = rest % 9;
            int ckl = cl*9 + k;
            const int4   co = *(const int4*)&c_off[rest*4];
            const float4 cw = *(const float4*)&c_w[rest*4];
            const float* fb = fT + c0 + cl;
            float g = cw.x*fb[co.x] + cw.y*fb[co.y] + cw.z*fb[co.z] + cw.w*fb[co.w];
            Gl[ckl*68 + p] = g;
        }
        // build W tile: 72 ck x 64 o
        int kk0 = cc * 72;
        #pragma unroll 2
        for (int i = 0; i < 18; ++i) {
            int e = t + i*256;
            int kkl = e >> 6, ol = e & 63;
            Wl[e] = dcn_wT[(kk0 + kkl)*256 + o0 + ol];
        }
        __syncthreads();
        #pragma unroll
        for (int kk = 0; kk < 72; ++kk) {
            float4 wv = *(const float4*)&Wl[kk*64 + to*4];
            float4 gv = *(const float4*)&Gl[kk*68 + tp*4];
            const float a[4] = {wv.x, wv.y, wv.z, wv.w};
            const float g4[4] = {gv.x, gv.y, gv.z, gv.w};
            #pragma unroll
            for (int i = 0; i < 4; ++i)
                #pragma unroll
                for (int j = 0; j < 4; ++j)
                    acc[i][j] += a[i] * g4[j];
        }
        __syncthreads();
    }

    // epilogue: bn2(y + dcn_b) + proj, relu (NaN-propagating), store
    #pragma unroll
    for (int i = 0; i < 4; ++i) {
        int o = o0 + to*4 + i;
        float sc = inv2f[o], bs = bias2f[o];
        int idx = ((b*256 + o)*64 + h)*64 + tp*4;
        float4 pj = *(const float4*)&proj[idx];
        float v0 = pj.x + acc[i][0]*sc + bs;
        float v1 = pj.y + acc[i][1]*sc + bs;
        float v2 = pj.z + acc[i][2]*sc + bs;
        float v3 = pj.w + acc[i][3]*sc + bs;
        // (v < 0) ? 0 : v  keeps NaN visible (fmaxf would silently zero it)
        float4 st = { v0 < 0.f ? 0.f : v0, v1 < 0.f ? 0.f : v1,
                      v2 < 0.f ? 0.f : v2, v3 < 0.f ? 0.f : v3 };
        *(float4*)&out[idx] = st;
    }
}

extern "C" void kernel_launch(void* const* d_in, const int* in_sizes, int n_in,
                              void* d_out, int out_size, void* d_ws, size_t ws_size,
                              hipStream_t stream)
{
    const float* feature = (const float*)d_in[0];
    const float* p1_w  = (const float*)d_in[1];
    const float* p1_b  = (const float*)d_in[2];
    const float* bn1_g = (const float*)d_in[3];
    const float* bn1_b = (const float*)d_in[4];
    const float* bn1_m = (const float*)d_in[5];
    const float* bn1_v = (const float*)d_in[6];
    const float* off_w = (const float*)d_in[7];
    const float* off_b = (const float*)d_in[8];
    const float* dcn_w = (const float*)d_in[9];
    const float* dcn_b = (const float*)d_in[10];
    const float* bn2_g = (const float*)d_in[11];
    const float* bn2_b = (const float*)d_in[12];
    const float* bn2_m = (const float*)d_in[13];
    const float* bn2_v = (const float*)d_in[14];

    float* ws = (float*)d_ws;
    float* proj   = ws;                 // 8388608 floats
    float* featT  = ws + 8388608;       // 8388608
    float* offbuf = ws + 16777216;      // 884736
    float* p1_wT  = ws + 17661952;      // 65536
    float* off_wT = ws + 17727488;      // 147456
    float* dcn_wT = ws + 17874944;      // 589824
    float* bias1f = ws + 18464768;      // 256
    float* inv2f  = ws + 18465024;      // 256
    float* bias2f = ws + 18465280;      // 256  (total ~73.9 MB)

    k_prep<<<7169, 256, 0, stream>>>(p1_w, p1_b, bn1_g, bn1_b, bn1_m, bn1_v,
                                     off_w, dcn_w, dcn_b, bn2_g, bn2_b, bn2_m, bn2_v,
                                     p1_wT, off_wT, dcn_wT, bias1f, inv2f, bias2f);
    k_featT<<<2048, 256, 0, stream>>>(feature, featT);
    k_proj<<<2048, 256, 0, stream>>>(feature, p1_wT, bias1f, proj);
    k_off<<<512, 256, 0, stream>>>(feature, proj, off_wT, off_b, offbuf);
    k_dcn<<<2048, 256, 0, stream>>>(featT, offbuf, dcn_wT, proj, inv2f, bias2f,
                                    (float*)d_out);
}

// Round 4
// 1171.593 us; speedup vs baseline: 1.4582x; 1.4582x over previous
//
#include <hip/hip_runtime.h>
#include <hip/hip_bf16.h>
#include <math.h>

typedef __attribute__((ext_vector_type(8))) short short8;
typedef __attribute__((ext_vector_type(4))) short short4v;
typedef __attribute__((ext_vector_type(4))) float f32x4;

__device__ __forceinline__ float bs2f(short s){
    union { unsigned u; float f; } x; x.u = ((unsigned)(unsigned short)s) << 16; return x.f;
}
__device__ __forceinline__ short f2bs(float f){
    union { float f; unsigned u; } x; x.f = f;
    unsigned r = x.u + 0x7fff + ((x.u >> 16) & 1);   // round-nearest-even
    return (short)(r >> 16);
}
__device__ __forceinline__ void gl2lds16(const void* g, void* l){
    __builtin_amdgcn_global_load_lds(
        (const __attribute__((address_space(1))) void*)g,
        (__attribute__((address_space(3))) void*)l, 16, 0, 0);
}

// ---------------- prep: BN folding + weight transposes/casts ----------------
// grid 7169 x 256
__global__ void k_prep(const float* __restrict__ p1_w, const float* __restrict__ p1_b,
                       const float* __restrict__ bn1_g, const float* __restrict__ bn1_b,
                       const float* __restrict__ bn1_m, const float* __restrict__ bn1_v,
                       const float* __restrict__ off_w,
                       const float* __restrict__ dcn_w, const float* __restrict__ dcn_b,
                       const float* __restrict__ bn2_g, const float* __restrict__ bn2_b,
                       const float* __restrict__ bn2_m, const float* __restrict__ bn2_v,
                       float* __restrict__ p1_wT, float* __restrict__ off_wT,
                       short* __restrict__ Wbf,
                       float* __restrict__ bias1f, float* __restrict__ inv2f,
                       float* __restrict__ bias2f)
{
    int blk = blockIdx.x, t = threadIdx.x;
    if (blk == 0) {
        float inv1 = bn1_g[t] / sqrtf(bn1_v[t] + 1e-5f);
        bias1f[t] = p1_b[t] * inv1 + bn1_b[t] - bn1_m[t] * inv1;
        float inv2 = bn2_g[t] / sqrtf(bn2_v[t] + 1e-5f);
        inv2f[t] = inv2;
        bias2f[t] = dcn_b[t] * inv2 + bn2_b[t] - bn2_m[t] * inv2;
    } else if (blk <= 256) {
        int ci = blk - 1;
        float inv1 = bn1_g[t] / sqrtf(bn1_v[t] + 1e-5f);
        p1_wT[ci*256 + t] = p1_w[t*256 + ci] * inv1;   // [ci][o], bn1 scale folded
    } else if (blk <= 2560) {
        int ck = blk - 257;                             // ck = c*9+tap (original order)
        int c = ck / 9, tap = ck % 9;
        // Wbf[o][tap*256+c] bf16: K reordered so sampling writes & frag reads contiguous
        Wbf[t*2304 + tap*256 + c] = f2bs(dcn_w[t*2304 + ck]);
    } else {
        int kk = blk - 2561;                            // kk = ci*9+tap, 0..4607
        if (t < 32) {
            int tt = (t < 27) ? t : 0;
            float v = off_w[tt*4608 + kk];
            off_wT[kk*32 + t] = (t < 27) ? v : 0.f;
        }
    }
}

// ---------------- transpose + flip -> bf16: featT[b][h][w][c] ----------------
// grid 2048 x 256  (8 b * 64 h * 4 c-groups)
__global__ void k_featT(const float* __restrict__ feature, short* __restrict__ featT)
{
    __shared__ float tile[64][65];
    int bb = blockIdx.x;
    int cg = bb & 3, h = (bb >> 2) & 63, b = bb >> 8;
    int c0 = cg * 64;
    int t = threadIdx.x;
    int lw = t & 63, li = t >> 6;
    #pragma unroll
    for (int j = 0; j < 16; ++j) {
        int cl = j*4 + li;
        tile[cl][63 - lw] = feature[((b*256 + c0 + cl)*64 + h)*64 + lw];
    }
    __syncthreads();
    #pragma unroll
    for (int j = 0; j < 16; ++j) {
        int wl = j*4 + li;
        featT[(((size_t)b*64 + h)*64 + wl)*256 + c0 + lw] = f2bs(tile[lw][wl]);
    }
}

// ---------------- proj: 1x1 conv + bn1 as GEMM 256 x 32768 x 256 ----------------
// grid 2048 x 256  (4 o-tiles * 512 (b,h) rows); bf16 output
__global__ void k_proj(const float* __restrict__ feature,
                       const float* __restrict__ p1_wT, const float* __restrict__ bias1f,
                       short* __restrict__ projb)
{
    __shared__ float A[16*64];   // [ci][o]
    __shared__ float Bt[16*64];  // [ci][w]
    int bb = blockIdx.x;
    int ot = bb & 3; int row = bb >> 2;
    int b = row >> 6, h = row & 63;
    int o0 = ot * 64;
    int t = threadIdx.x;
    int to = t & 15, tp = t >> 4;
    int li = t >> 6, lw = t & 63;
    float acc[4][4] = {};
    for (int ci0 = 0; ci0 < 256; ci0 += 16) {
        #pragma unroll
        for (int j = 0; j < 4; ++j) {
            int r = j*4 + li;
            A[r*64 + lw]  = p1_wT[(ci0 + r)*256 + o0 + lw];
            Bt[r*64 + lw] = feature[((b*256 + ci0 + r)*64 + h)*64 + lw];
        }
        __syncthreads();
        #pragma unroll
        for (int kk = 0; kk < 16; ++kk) {
            const float4 av = *(const float4*)&A[kk*64 + to*4];
            const float4 bv = *(const float4*)&Bt[kk*64 + tp*4];
            const float a[4] = {av.x, av.y, av.z, av.w};
            const float bv4[4] = {bv.x, bv.y, bv.z, bv.w};
            #pragma unroll
            for (int i = 0; i < 4; ++i)
                #pragma unroll
                for (int j = 0; j < 4; ++j)
                    acc[i][j] += a[i] * bv4[j];
        }
        __syncthreads();
    }
    #pragma unroll
    for (int i = 0; i < 4; ++i) {
        int o = o0 + to*4 + i;
        float bs = bias1f[o];
        short4v st;
        st.x = f2bs(acc[i][0]+bs); st.y = f2bs(acc[i][1]+bs);
        st.z = f2bs(acc[i][2]+bs); st.w = f2bs(acc[i][3]+bs);
        *(short4v*)&projb[((b*256 + o)*64 + h)*64 + tp*4] = st;
    }
}

// ---------------- off: 3x3 conv (concat[flip,proj] 512ch -> 27) as GEMM -------
// grid 512 x 256  ((b,h) rows), oc padded to 32
__global__ void k_off(const float* __restrict__ feature,
                      const short* __restrict__ projb,
                      const float* __restrict__ off_wT, const float* __restrict__ off_b,
                      float* __restrict__ offv)
{
    __shared__ float Wl[36*32];  // [kk][oc]
    __shared__ float Il[36*64];  // [kk][w]
    int bb = blockIdx.x;
    int b = bb >> 6, h = bb & 63;
    int t = threadIdx.x;
    int to = t & 7, tp = t >> 3;   // to: oc/4, tp: w/2
    float acc[4][2] = {};
    for (int kk0 = 0; kk0 < 4608; kk0 += 36) {
        for (int e = t; e < 36*64; e += 256) {
            int kkl = e >> 6, pl = e & 63;
            int kk = kk0 + kkl;
            int ci = kk / 9, tap = kk % 9;
            int y = h + tap/3 - 1;
            int x = pl + tap%3 - 1;
            float v = 0.f;
            if (y >= 0 && y < 64 && x >= 0 && x < 64) {
                if (ci < 256) v = feature[((b*256 + ci)*64 + y)*64 + (63 - x)];
                else          v = bs2f(projb[((b*256 + (ci-256))*64 + y)*64 + x]);
            }
            Il[kkl*64 + pl] = v;
        }
        for (int e = t; e < 36*32; e += 256) {
            Wl[e] = off_wT[kk0*32 + e];
        }
        __syncthreads();
        #pragma unroll
        for (int kk = 0; kk < 36; ++kk) {
            float4 wv = *(const float4*)&Wl[kk*32 + to*4];
            float2 iv = *(const float2*)&Il[kk*64 + tp*2];
            acc[0][0] += wv.x*iv.x; acc[0][1] += wv.x*iv.y;
            acc[1][0] += wv.y*iv.x; acc[1][1] += wv.y*iv.y;
            acc[2][0] += wv.z*iv.x; acc[2][1] += wv.z*iv.y;
            acc[3][0] += wv.w*iv.x; acc[3][1] += wv.w*iv.y;
        }
        __syncthreads();
    }
    #pragma unroll
    for (int i = 0; i < 4; ++i) {
        int oc = to*4 + i;
        if (oc < 27) {
            float ob = off_b[oc];
            int idx = ((b*27 + oc)*64 + h)*64 + tp*2;
            offv[idx]   = acc[i][0] + ob;
            offv[idx+1] = acc[i][1] + ob;
        }
    }
}

// ---------------- sample: masked bilinear im2col -> G[pos][tap*256+c] bf16 ----
// grid 512 x 256  ((b,h) rows)
__global__ void k_sample(const short* __restrict__ featT,   // bf16 [b][h][w][c]
                         const float* __restrict__ offv,
                         short* __restrict__ G)
{
    __shared__ int   c_off[576*4];
    __shared__ float c_w[576*4];
    int bb = blockIdx.x;
    int b = bb >> 6, h = bb & 63;
    int t = threadIdx.x;

    for (int e = t; e < 576; e += 256) {
        int p = e / 9, k = e % 9;
        int base = (b*27)*4096 + h*64 + p;
        float dy = offv[base + k*4096];
        float dx = offv[base + (9+k)*4096];
        float ms = offv[base + (18+k)*4096];
        ms = 1.f / (1.f + expf(-ms));
        float py = (float)h + (float)(k/3 - 1) + dy;
        float px = (float)p + (float)(k%3 - 1) + dx;
        float y0f = floorf(py), x0f = floorf(px);
        float wy = py - y0f, wx = px - x0f;
        int y0 = (int)y0f, x0 = (int)x0f;
        int y1 = y0 + 1, x1 = x0 + 1;
        float vy0 = (y0 >= 0 && y0 < 64) ? 1.f : 0.f;
        float vy1 = (y1 >= 0 && y1 < 64) ? 1.f : 0.f;
        float vx0 = (x0 >= 0 && x0 < 64) ? 1.f : 0.f;
        float vx1 = (x1 >= 0 && x1 < 64) ? 1.f : 0.f;
        int y0c = min(max(y0,0),63), y1c = min(max(y1,0),63);
        int x0c = min(max(x0,0),63), x1c = min(max(x1,0),63);
        c_off[e*4+0] = (y0c*64 + x0c)*256;
        c_off[e*4+1] = (y0c*64 + x1c)*256;
        c_off[e*4+2] = (y1c*64 + x0c)*256;
        c_off[e*4+3] = (y1c*64 + x1c)*256;
        c_w[e*4+0] = ms * (1.f-wy)*(1.f-wx) * vy0*vx0;
        c_w[e*4+1] = ms * (1.f-wy)*wx       * vy0*vx1;
        c_w[e*4+2] = ms * wy*(1.f-wx)       * vy1*vx0;
        c_w[e*4+3] = ms * wy*wx             * vy1*vx1;
    }
    __syncthreads();

    int tc = t & 63, tg = t >> 6;                 // lane over c: coalesced
    const short* fT = featT + (size_t)b*64*64*256;
    size_t rb = ((size_t)b*4096 + h*64);
    for (int pi = 0; pi < 16; ++pi) {
        int p = tg + pi*4;                         // wave-uniform p
        size_t grow = (rb + p)*2304;
        #pragma unroll
        for (int k = 0; k < 9; ++k) {
            int e = p*9 + k;
            const int4   co = *(const int4*)&c_off[e*4];
            const float4 cw = *(const float4*)&c_w[e*4];
            #pragma unroll
            for (int cg = 0; cg < 4; ++cg) {
                int c = cg*64 + tc;
                float g = cw.x*bs2f(fT[co.x + c]) + cw.y*bs2f(fT[co.y + c])
                        + cw.z*bs2f(fT[co.z + c]) + cw.w*bs2f(fT[co.w + c]);
                G[grow + k*256 + c] = f2bs(g);
            }
        }
    }
}

// ---------------- dcn GEMM via bf16 MFMA: C[o][pos] + epilogue ----------------
// M = o (256, 2 tiles), N = pos (32768, 256 tiles), K = 2304 (72 chunks of 32)
// grid 512 x 256 (4 waves); m97 structure: global_load_lds(16B) staging
__global__ __launch_bounds__(256) void k_gemm(
    const short* __restrict__ G,      // [32768][2304] bf16
    const short* __restrict__ Wbf,    // [256][2304] bf16
    const short* __restrict__ projb,
    const float* __restrict__ inv2f, const float* __restrict__ bias2f,
    float* __restrict__ out)
{
    __shared__ short Ash[128*32];   // W tile [o_local][k]
    __shared__ short Bsh[128*32];   // G tile [pos_local][k]
    int bid = blockIdx.x;
    int mt = bid & 1;          // o tile
    int nt = bid >> 1;         // pos tile
    int m0 = mt*128, n0 = nt*128;
    int t = threadIdx.x;
    int lane = t & 63, w = t >> 6;
    int ln = lane & 15, q = lane >> 4;
    int wr = w & 1, wc = w >> 1;

    const short* gA = Wbf + (size_t)(m0 + w*16 + (lane>>2))*2304 + (lane&3)*8;
    const short* gB = G   + (size_t)(n0 + w*16 + (lane>>2))*2304 + (lane&3)*8;
    short* lA = Ash + (w*16)*32;   // wave-uniform base; HW adds lane*16B
    short* lB = Bsh + (w*16)*32;

    f32x4 acc[4][4] = {};

    for (int kt = 0; kt < 72; ++kt) {
        gl2lds16(gA,                 lA);
        gl2lds16(gA + 64*2304,       lA + 64*32);
        gl2lds16(gB,                 lB);
        gl2lds16(gB + 64*2304,       lB + 64*32);
        gA += 32; gB += 32;
        __syncthreads();
        short8 af[4], bfr[4];
        #pragma unroll
        for (int i = 0; i < 4; ++i)
            af[i] = *(const short8*)&Ash[(wr*64 + i*16 + ln)*32 + q*8];
        #pragma unroll
        for (int j = 0; j < 4; ++j)
            bfr[j] = *(const short8*)&Bsh[(wc*64 + j*16 + ln)*32 + q*8];
        #pragma unroll
        for (int i = 0; i < 4; ++i)
            #pragma unroll
            for (int j = 0; j < 4; ++j)
                acc[i][j] = __builtin_amdgcn_mfma_f32_16x16x32_bf16(af[i], bfr[j], acc[i][j], 0, 0, 0);
        __syncthreads();
    }

    // epilogue: bn2 + residual + relu; C/D: col(lane&15)=pos (coalesced), row=q*4+r = o
    #pragma unroll
    for (int i = 0; i < 4; ++i) {
        int ob = m0 + wr*64 + i*16 + q*4;
        #pragma unroll
        for (int j = 0; j < 4; ++j) {
            int pos = n0 + wc*64 + j*16 + ln;
            int b = pos >> 12, hw = pos & 4095;
            #pragma unroll
            for (int r = 0; r < 4; ++r) {
                int o = ob + r;
                size_t idx = ((size_t)(b*256 + o))*4096 + hw;
                float v = bs2f(projb[idx]) + acc[i][j][r]*inv2f[o] + bias2f[o];
                out[idx] = v < 0.f ? 0.f : v;   // NaN-propagating relu
            }
        }
    }
}

extern "C" void kernel_launch(void* const* d_in, const int* in_sizes, int n_in,
                              void* d_out, int out_size, void* d_ws, size_t ws_size,
                              hipStream_t stream)
{
    const float* feature = (const float*)d_in[0];
    const float* p1_w  = (const float*)d_in[1];
    const float* p1_b  = (const float*)d_in[2];
    const float* bn1_g = (const float*)d_in[3];
    const float* bn1_b = (const float*)d_in[4];
    const float* bn1_m = (const float*)d_in[5];
    const float* bn1_v = (const float*)d_in[6];
    const float* off_w = (const float*)d_in[7];
    const float* off_b = (const float*)d_in[8];
    const float* dcn_w = (const float*)d_in[9];
    const float* dcn_b = (const float*)d_in[10];
    const float* bn2_g = (const float*)d_in[11];
    const float* bn2_b = (const float*)d_in[12];
    const float* bn2_m = (const float*)d_in[13];
    const float* bn2_v = (const float*)d_in[14];

    // Workspace layout (float-slot offsets). Total 47,530,752 floats = 190.1 MB
    // (round 3 wrote 194.3 MB without fault, so this range is known-writable).
    float* ws = (float*)d_ws;
    short* projb   = (short*)ws;               // 8,388,608 bf16 = 4,194,304 f  [0, 4194304)
    short* featTb  = (short*)(ws + 4194304);   // 8,388,608 bf16 = 4,194,304 f  [4194304, 8388608)
    float* offbuf  = ws + 8388608;             //   884,736 f                   [8388608, 9273344)
    float* p1_wT   = ws + 9273344;             //    65,536 f
    float* off_wT  = ws + 9338880;             //   147,456 f
    short* Wbf     = (short*)(ws + 9486336);   //   589,824 bf16 = 294,912 f
    float* bias1f  = ws + 9781248;             //       256
    float* inv2f   = ws + 9781504;             //       256
    float* bias2f  = ws + 9781760;             //       256
    short* G       = (short*)(ws + 9782016);   // 75,497,472 bf16 = 37,748,736 f [9782016, 47530752)

    k_prep<<<7169, 256, 0, stream>>>(p1_w, p1_b, bn1_g, bn1_b, bn1_m, bn1_v,
                                     off_w, dcn_w, dcn_b, bn2_g, bn2_b, bn2_m, bn2_v,
                                     p1_wT, off_wT, Wbf, bias1f, inv2f, bias2f);
    k_featT<<<2048, 256, 0, stream>>>(feature, featTb);
    k_proj<<<2048, 256, 0, stream>>>(feature, p1_wT, bias1f, projb);
    k_off<<<512, 256, 0, stream>>>(feature, projb, off_wT, off_b, offbuf);
    k_sample<<<512, 256, 0, stream>>>(featTb, offbuf, G);
    k_gemm<<<512, 256, 0, stream>>>(G, Wbf, projb, inv2f, bias2f, (float*)d_out);
}

// Round 5
// 621.569 us; speedup vs baseline: 2.7486x; 1.8849x over previous
//
#include <hip/hip_runtime.h>
#include <hip/hip_bf16.h>
#include <math.h>

typedef __attribute__((ext_vector_type(8))) short short8;
typedef __attribute__((ext_vector_type(4))) short short4v;
typedef __attribute__((ext_vector_type(4))) float f32x4;

__device__ __forceinline__ float bs2f(short s){
    union { unsigned u; float f; } x; x.u = ((unsigned)(unsigned short)s) << 16; return x.f;
}
__device__ __forceinline__ short f2bs(float f){
    union { float f; unsigned u; } x; x.f = f;
    unsigned r = x.u + 0x7fff + ((x.u >> 16) & 1);   // round-nearest-even
    return (short)(r >> 16);
}
__device__ __forceinline__ void gl2lds16(const void* g, void* l){
    __builtin_amdgcn_global_load_lds(
        (const __attribute__((address_space(1))) void*)g,
        (__attribute__((address_space(3))) void*)l, 16, 0, 0);
}

// Xpad[b][y][x][c]: y,x in [0,66), c in [0,512). Interior (y=h+1,x=w+1).
// c<256: flipped feature (= feature[b][c][h][63-w]); c>=256: proj.
#define XPB ((size_t)66*66*512)

// ---------------- prep: BN folding + weight transposes/casts ----------------
// grid 7169 x 256
__global__ void k_prep(const float* __restrict__ p1_w, const float* __restrict__ p1_b,
                       const float* __restrict__ bn1_g, const float* __restrict__ bn1_b,
                       const float* __restrict__ bn1_m, const float* __restrict__ bn1_v,
                       const float* __restrict__ off_w,
                       const float* __restrict__ dcn_w, const float* __restrict__ dcn_b,
                       const float* __restrict__ bn2_g, const float* __restrict__ bn2_b,
                       const float* __restrict__ bn2_m, const float* __restrict__ bn2_v,
                       short* __restrict__ p1_wb, short* __restrict__ Woffb,
                       short* __restrict__ Wbf,
                       float* __restrict__ bias1f, float* __restrict__ inv2f,
                       float* __restrict__ bias2f)
{
    int blk = blockIdx.x, t = threadIdx.x;
    if (blk == 0) {
        float inv1 = bn1_g[t] / sqrtf(bn1_v[t] + 1e-5f);
        bias1f[t] = p1_b[t] * inv1 + bn1_b[t] - bn1_m[t] * inv1;
        float inv2 = bn2_g[t] / sqrtf(bn2_v[t] + 1e-5f);
        inv2f[t] = inv2;
        bias2f[t] = dcn_b[t] * inv2 + bn2_b[t] - bn2_m[t] * inv2;
    } else if (blk <= 256) {
        int ci = blk - 1;
        float inv1 = bn1_g[t] / sqrtf(bn1_v[t] + 1e-5f);
        p1_wb[t*256 + ci] = f2bs(p1_w[t*256 + ci] * inv1);   // [o][ci], bn1 folded
    } else if (blk <= 2560) {
        int ck = blk - 257;                             // ck = c*9+tap (original order)
        int c = ck / 9, tap = ck % 9;
        Wbf[t*2304 + tap*256 + c] = f2bs(dcn_w[t*2304 + ck]);  // [o][tap*256+c]
    } else {
        int e = blk - 2561;                             // e = tap*512+ci (new K order)
        if (t < 32) {
            int tap = e >> 9, ci = e & 511;
            float v = off_w[((t < 27) ? t : 0)*4608 + ci*9 + tap];
            Woffb[t*4608 + e] = (t < 27) ? f2bs(v) : (short)0;  // [oc pad32][tap*512+ci]
        }
    }
}

// ---------------- halo zero: Xpad boundary cells (260/b) ----------------
// grid 2080 x 256; each thread zeroes one uint (2 bf16)
__global__ void k_halo(unsigned* __restrict__ Xpad)
{
    int blk = blockIdx.x, t = threadIdx.x;
    int b = blk / 260, i = blk % 260;
    int y, x;
    if (i < 66)       { y = 0;  x = i; }
    else if (i < 132) { y = 65; x = i - 66; }
    else { int j = i - 132; y = 1 + (j >> 1); x = (j & 1) * 65; }
    Xpad[((size_t)(b*66 + y)*66 + x)*256 + t] = 0u;
}

// ---------------- transpose+flip -> Xpad flip half (bf16, channels-last) -----
// grid 2048 x 256  (8 b * 64 h * 4 c-groups)
__global__ void k_featT(const float* __restrict__ feature, short* __restrict__ Xpad)
{
    __shared__ float tile[64][65];
    int bb = blockIdx.x;
    int cg = bb & 3, h = (bb >> 2) & 63, b = bb >> 8;
    int c0 = cg * 64;
    int t = threadIdx.x;
    int lw = t & 63, li = t >> 6;
    #pragma unroll
    for (int j = 0; j < 16; ++j) {
        int cl = j*4 + li;
        tile[cl][63 - lw] = feature[((b*256 + c0 + cl)*64 + h)*64 + lw];
    }
    __syncthreads();
    #pragma unroll
    for (int j = 0; j < 16; ++j) {
        int wl = j*4 + li;
        Xpad[((size_t)(b*66 + h+1)*66 + (wl+1))*512 + c0 + lw] = f2bs(tile[lw][wl]);
    }
}

// ---------------- proj via MFMA: M=256(o) N=32768(pos) K=256(ci) --------------
// grid 512 (2 m-tiles x 256 n-tiles) x 256; writes Xpad proj half
__global__ __launch_bounds__(256) void k_projm(
    short* Xpad, const short* __restrict__ p1_wb, const float* __restrict__ bias1f)
{
    __shared__ short Ash[128*32];
    __shared__ short Bsh[128*32];
    int bid = blockIdx.x;
    int mt = bid & 1, nt = bid >> 1;
    int m0 = mt*128, n0 = nt*128;
    int t = threadIdx.x;
    int lane = t & 63, w = t >> 6;
    int ln = lane & 15, q = lane >> 4;
    int wr = w & 1, wc = w >> 1;
    int ccol = (lane & 3)*8;

    const short* gA1 = p1_wb + (size_t)(m0 + w*16 + (lane>>2))*256 + ccol;
    const short* gA2 = gA1 + 64*256;
    int pos1 = n0 + w*16 + (lane>>2);
    int pos2 = pos1 + 64;
    int b1 = pos1 >> 12, hw1 = pos1 & 4095;
    int b2 = pos2 >> 12, hw2 = pos2 & 4095;
    const short* gB1 = Xpad + ((size_t)(b1*66 + (hw1>>6) + 1)*66 + (64 - (hw1 & 63)))*512 + ccol;
    const short* gB2 = Xpad + ((size_t)(b2*66 + (hw2>>6) + 1)*66 + (64 - (hw2 & 63)))*512 + ccol;
    short* lA = Ash + (w*16)*32;
    short* lB = Bsh + (w*16)*32;

    f32x4 acc[4][4] = {};
    for (int kt = 0; kt < 8; ++kt) {
        gl2lds16(gA1, lA);
        gl2lds16(gA2, lA + 64*32);
        gl2lds16(gB1, lB);
        gl2lds16(gB2, lB + 64*32);
        gA1 += 32; gA2 += 32; gB1 += 32; gB2 += 32;
        __syncthreads();
        short8 af[4], bfr[4];
        #pragma unroll
        for (int i = 0; i < 4; ++i)
            af[i] = *(const short8*)&Ash[(wr*64 + i*16 + ln)*32 + q*8];
        #pragma unroll
        for (int j = 0; j < 4; ++j)
            bfr[j] = *(const short8*)&Bsh[(wc*64 + j*16 + ln)*32 + q*8];
        #pragma unroll
        for (int i = 0; i < 4; ++i)
            #pragma unroll
            for (int j = 0; j < 4; ++j)
                acc[i][j] = __builtin_amdgcn_mfma_f32_16x16x32_bf16(af[i], bfr[j], acc[i][j], 0, 0, 0);
        __syncthreads();
    }
    // epilogue: row=o(q*4+r), col=pos(ln); store bf16 into Xpad[...][256+o]
    #pragma unroll
    for (int i = 0; i < 4; ++i) {
        int ob = m0 + wr*64 + i*16 + q*4;
        #pragma unroll
        for (int j = 0; j < 4; ++j) {
            int pos = n0 + wc*64 + j*16 + ln;
            int b = pos >> 12, hw = pos & 4095;
            size_t xb = ((size_t)(b*66 + (hw>>6) + 1)*66 + (hw & 63) + 1)*512 + 256 + ob;
            short4v st;
            st.x = f2bs(acc[i][j][0] + bias1f[ob]);
            st.y = f2bs(acc[i][j][1] + bias1f[ob+1]);
            st.z = f2bs(acc[i][j][2] + bias1f[ob+2]);
            st.w = f2bs(acc[i][j][3] + bias1f[ob+3]);
            *(short4v*)&Xpad[xb] = st;
        }
    }
}

// ---------------- offset conv via MFMA: M=32(27 oc) N=64(x) K=4608 ------------
// grid 512 ((b,h) rows) x 256; K-chunk 32 within one tap -> shifted Xpad rows
__global__ __launch_bounds__(256) void k_offm(
    const short* __restrict__ Xpad, const short* __restrict__ Woffb,
    const float* __restrict__ off_b, float* __restrict__ offv)
{
    __shared__ short Ash[32*32];
    __shared__ short Bsh[64*32];
    int bid = blockIdx.x;
    int b = bid >> 6, h = bid & 63;
    int t = threadIdx.x;
    int lane = t & 63, w = t >> 6;
    int ln = lane & 15, q = lane >> 4;
    int wr = w & 1, wc = w >> 1;
    int row = w*16 + (lane >> 2);      // staging row (A: oc, B: x-pos)
    int ccol = (lane & 3)*8;
    const short* xb = Xpad + (size_t)b*XPB;

    f32x4 acc[2] = {};
    for (int kc = 0; kc < 144; ++kc) {
        int tap = kc >> 4, c0 = (kc & 15) << 5;
        int dy = tap/3 - 1, dx = tap%3 - 1;
        const short* gB = xb + ((size_t)(h + 1 + dy)*66 + (row + dx + 1))*512 + c0 + ccol;
        gl2lds16(gB, Bsh + (w*16)*32);
        if (w < 2) {
            const short* gA = Woffb + (size_t)row*4608 + kc*32 + ccol;
            gl2lds16(gA, Ash + (w*16)*32);
        }
        __syncthreads();
        short8 af = *(const short8*)&Ash[(wr*16 + ln)*32 + q*8];
        #pragma unroll
        for (int j = 0; j < 2; ++j) {
            short8 bfr = *(const short8*)&Bsh[((wc*2 + j)*16 + ln)*32 + q*8];
            acc[j] = __builtin_amdgcn_mfma_f32_16x16x32_bf16(af, bfr, acc[j], 0, 0, 0);
        }
        __syncthreads();
    }
    #pragma unroll
    for (int j = 0; j < 2; ++j) {
        int x = (wc*2 + j)*16 + ln;
        #pragma unroll
        for (int r = 0; r < 4; ++r) {
            int oc = wr*16 + q*4 + r;
            if (oc < 27)
                offv[((b*27 + oc)*64 + h)*64 + x] = acc[j][r] + off_b[oc];
        }
    }
}

// ---------------- sample: masked bilinear im2col -> G[pos][tap*256+c] bf16 ----
// grid 512 x 256  ((b,h) rows); gathers from Xpad flip half
__global__ void k_sample(const short* __restrict__ Xpad,
                         const float* __restrict__ offv,
                         short* __restrict__ G)
{
    __shared__ int   c_off[576*4];
    __shared__ float c_w[576*4];
    int bb = blockIdx.x;
    int b = bb >> 6, h = bb & 63;
    int t = threadIdx.x;

    for (int e = t; e < 576; e += 256) {
        int p = e / 9, k = e % 9;
        int base = (b*27)*4096 + h*64 + p;
        float dy = offv[base + k*4096];
        float dx = offv[base + (9+k)*4096];
        float ms = offv[base + (18+k)*4096];
        ms = 1.f / (1.f + expf(-ms));
        float py = (float)h + (float)(k/3 - 1) + dy;
        float px = (float)p + (float)(k%3 - 1) + dx;
        float y0f = floorf(py), x0f = floorf(px);
        float wy = py - y0f, wx = px - x0f;
        int y0 = (int)y0f, x0 = (int)x0f;
        int y1 = y0 + 1, x1 = x0 + 1;
        float vy0 = (y0 >= 0 && y0 < 64) ? 1.f : 0.f;
        float vy1 = (y1 >= 0 && y1 < 64) ? 1.f : 0.f;
        float vx0 = (x0 >= 0 && x0 < 64) ? 1.f : 0.f;
        float vx1 = (x1 >= 0 && x1 < 64) ? 1.f : 0.f;
        int y0c = min(max(y0,0),63), y1c = min(max(y1,0),63);
        int x0c = min(max(x0,0),63), x1c = min(max(x1,0),63);
        c_off[e*4+0] = ((y0c+1)*66 + x0c+1)*512;
        c_off[e*4+1] = ((y0c+1)*66 + x1c+1)*512;
        c_off[e*4+2] = ((y1c+1)*66 + x0c+1)*512;
        c_off[e*4+3] = ((y1c+1)*66 + x1c+1)*512;
        c_w[e*4+0] = ms * (1.f-wy)*(1.f-wx) * vy0*vx0;
        c_w[e*4+1] = ms * (1.f-wy)*wx       * vy0*vx1;
        c_w[e*4+2] = ms * wy*(1.f-wx)       * vy1*vx0;
        c_w[e*4+3] = ms * wy*wx             * vy1*vx1;
    }
    __syncthreads();

    int tc = t & 63, tg = t >> 6;
    const short* fT = Xpad + (size_t)b*XPB;
    size_t rb = ((size_t)b*4096 + h*64);
    for (int pi = 0; pi < 16; ++pi) {
        int p = tg + pi*4;                         // wave-uniform p
        size_t grow = (rb + p)*2304;
        #pragma unroll
        for (int k = 0; k < 9; ++k) {
            int e = p*9 + k;
            const int4   co = *(const int4*)&c_off[e*4];
            const float4 cw = *(const float4*)&c_w[e*4];
            #pragma unroll
            for (int cg = 0; cg < 4; ++cg) {
                int c = cg*64 + tc;
                float g = cw.x*bs2f(fT[co.x + c]) + cw.y*bs2f(fT[co.y + c])
                        + cw.z*bs2f(fT[co.z + c]) + cw.w*bs2f(fT[co.w + c]);
                G[grow + k*256 + c] = f2bs(g);
            }
        }
    }
}

// ---------------- dcn GEMM via bf16 MFMA: C[o][pos] + epilogue ----------------
// M=256(o) 2 tiles, N=32768(pos) 256 tiles, K=2304 (72 chunks of 32)
__global__ __launch_bounds__(256) void k_gemm(
    const short* __restrict__ G,      // [32768][2304] bf16
    const short* __restrict__ Wbf,    // [256][2304] bf16
    const short* __restrict__ Xpad,   // residual: proj half
    const float* __restrict__ inv2f, const float* __restrict__ bias2f,
    float* __restrict__ out)
{
    __shared__ short Ash[128*32];
    __shared__ short Bsh[128*32];
    int bid = blockIdx.x;
    int mt = bid & 1, nt = bid >> 1;
    int m0 = mt*128, n0 = nt*128;
    int t = threadIdx.x;
    int lane = t & 63, w = t >> 6;
    int ln = lane & 15, q = lane >> 4;
    int wr = w & 1, wc = w >> 1;

    const short* gA = Wbf + (size_t)(m0 + w*16 + (lane>>2))*2304 + (lane&3)*8;
    const short* gB = G   + (size_t)(n0 + w*16 + (lane>>2))*2304 + (lane&3)*8;
    short* lA = Ash + (w*16)*32;
    short* lB = Bsh + (w*16)*32;

    f32x4 acc[4][4] = {};
    for (int kt = 0; kt < 72; ++kt) {
        gl2lds16(gA,           lA);
        gl2lds16(gA + 64*2304, lA + 64*32);
        gl2lds16(gB,           lB);
        gl2lds16(gB + 64*2304, lB + 64*32);
        gA += 32; gB += 32;
        __syncthreads();
        short8 af[4], bfr[4];
        #pragma unroll
        for (int i = 0; i < 4; ++i)
            af[i] = *(const short8*)&Ash[(wr*64 + i*16 + ln)*32 + q*8];
        #pragma unroll
        for (int j = 0; j < 4; ++j)
            bfr[j] = *(const short8*)&Bsh[(wc*64 + j*16 + ln)*32 + q*8];
        #pragma unroll
        for (int i = 0; i < 4; ++i)
            #pragma unroll
            for (int j = 0; j < 4; ++j)
                acc[i][j] = __builtin_amdgcn_mfma_f32_16x16x32_bf16(af[i], bfr[j], acc[i][j], 0, 0, 0);
        __syncthreads();
    }

    // epilogue: bn2 + residual(from Xpad proj half) + relu
    #pragma unroll
    for (int i = 0; i < 4; ++i) {
        int ob = m0 + wr*64 + i*16 + q*4;
        #pragma unroll
        for (int j = 0; j < 4; ++j) {
            int pos = n0 + wc*64 + j*16 + ln;
            int b = pos >> 12, hw = pos & 4095;
            size_t xb = ((size_t)(b*66 + (hw>>6) + 1)*66 + (hw & 63) + 1)*512 + 256 + ob;
            short4v pr = *(const short4v*)&Xpad[xb];
            #pragma unroll
            for (int r = 0; r < 4; ++r) {
                int o = ob + r;
                size_t idx = ((size_t)(b*256 + o))*4096 + hw;
                float rs = bs2f(((const short*)&pr)[r]);
                float v = rs + acc[i][j][r]*inv2f[o] + bias2f[o];
                out[idx] = v < 0.f ? 0.f : v;   // NaN-propagating relu
            }
        }
    }
}

extern "C" void kernel_launch(void* const* d_in, const int* in_sizes, int n_in,
                              void* d_out, int out_size, void* d_ws, size_t ws_size,
                              hipStream_t stream)
{
    const float* feature = (const float*)d_in[0];
    const float* p1_w  = (const float*)d_in[1];
    const float* p1_b  = (const float*)d_in[2];
    const float* bn1_g = (const float*)d_in[3];
    const float* bn1_b = (const float*)d_in[4];
    const float* bn1_m = (const float*)d_in[5];
    const float* bn1_v = (const float*)d_in[6];
    const float* off_w = (const float*)d_in[7];
    const float* off_b = (const float*)d_in[8];
    const float* dcn_w = (const float*)d_in[9];
    const float* dcn_b = (const float*)d_in[10];
    const float* bn2_g = (const float*)d_in[11];
    const float* bn2_b = (const float*)d_in[12];
    const float* bn2_m = (const float*)d_in[13];
    const float* bn2_v = (const float*)d_in[14];

    // Workspace (float-slot offsets). Total 47,956,736 f = 191.8 MB
    // (round 3 wrote 194.3 MB in-range without corruption -> known-writable).
    float* ws = (float*)d_ws;
    short* Xpad   = (short*)ws;                 // 17,842,176 sh = 8,921,088 f
    float* offbuf = ws + 8921088;               //    884,736 f
    short* p1_wb  = (short*)(ws + 9805824);     //     65,536 sh = 32,768 f
    short* Woffb  = (short*)(ws + 9838592);     //    147,456 sh = 73,728 f
    short* Wbf    = (short*)(ws + 9912320);     //    589,824 sh = 294,912 f
    float* bias1f = ws + 10207232;              //        256
    float* inv2f  = ws + 10207488;              //        256
    float* bias2f = ws + 10207744;              //        256
    short* G      = (short*)(ws + 10208000);    // 75,497,472 sh = 37,748,736 f

    k_prep<<<7169, 256, 0, stream>>>(p1_w, p1_b, bn1_g, bn1_b, bn1_m, bn1_v,
                                     off_w, dcn_w, dcn_b, bn2_g, bn2_b, bn2_m, bn2_v,
                                     p1_wb, Woffb, Wbf, bias1f, inv2f, bias2f);
    k_halo<<<2080, 256, 0, stream>>>((unsigned*)Xpad);
    k_featT<<<2048, 256, 0, stream>>>(feature, Xpad);
    k_projm<<<512, 256, 0, stream>>>(Xpad, p1_wb, bias1f);
    k_offm<<<512, 256, 0, stream>>>(Xpad, Woffb, off_b, offbuf);
    k_sample<<<512, 256, 0, stream>>>(Xpad, offbuf, G);
    k_gemm<<<512, 256, 0, stream>>>(G, Wbf, Xpad, inv2f, bias2f, (float*)d_out);
}

// Round 6
// 311.414 us; speedup vs baseline: 5.4860x; 1.9960x over previous
//
#include <hip/hip_runtime.h>
#include <hip/hip_bf16.h>
#include <math.h>

typedef __attribute__((ext_vector_type(8))) short short8;
typedef __attribute__((ext_vector_type(4))) short short4v;
typedef __attribute__((ext_vector_type(4))) float f32x4;

__device__ __forceinline__ float bs2f(short s){
    union { unsigned u; float f; } x; x.u = ((unsigned)(unsigned short)s) << 16; return x.f;
}
__device__ __forceinline__ short f2bs(float f){
    union { float f; unsigned u; } x; x.f = f;
    unsigned r = x.u + 0x7fff + ((x.u >> 16) & 1);   // round-nearest-even
    return (short)(r >> 16);
}
__device__ __forceinline__ float blo(unsigned u){
    union { unsigned u; float f; } x; x.u = u << 16; return x.f;
}
__device__ __forceinline__ float bhi(unsigned u){
    union { unsigned u; float f; } x; x.u = u & 0xffff0000u; return x.f;
}
__device__ __forceinline__ unsigned pack2(float lo, float hi){
    union { float f; unsigned u; } a, b; a.f = lo; b.f = hi;
    unsigned rl = a.u + 0x7fff + ((a.u >> 16) & 1);
    unsigned rh = b.u + 0x7fff + ((b.u >> 16) & 1);
    return (rl >> 16) | (rh & 0xffff0000u);
}
__device__ __forceinline__ void gl2lds16(const void* g, void* l){
    __builtin_amdgcn_global_load_lds(
        (const __attribute__((address_space(1))) void*)g,
        (__attribute__((address_space(3))) void*)l, 16, 0, 0);
}

// Xpad[b][y][x][c]: y,x in [0,66), c in [0,512). Interior (y=h+1,x=w+1).
// c<256: flipped feature (= feature[b][c][h][63-w]); c>=256: proj.
#define XPB ((size_t)66*66*512)

// ---------------- prep: BN folding + weight transposes/casts ----------------
// grid 7169 x 256
__global__ void k_prep(const float* __restrict__ p1_w, const float* __restrict__ p1_b,
                       const float* __restrict__ bn1_g, const float* __restrict__ bn1_b,
                       const float* __restrict__ bn1_m, const float* __restrict__ bn1_v,
                       const float* __restrict__ off_w,
                       const float* __restrict__ dcn_w, const float* __restrict__ dcn_b,
                       const float* __restrict__ bn2_g, const float* __restrict__ bn2_b,
                       const float* __restrict__ bn2_m, const float* __restrict__ bn2_v,
                       short* __restrict__ p1_wb, short* __restrict__ Woffb,
                       short* __restrict__ Wbf,
                       float* __restrict__ bias1f, float* __restrict__ inv2f,
                       float* __restrict__ bias2f)
{
    int blk = blockIdx.x, t = threadIdx.x;
    if (blk == 0) {
        float inv1 = bn1_g[t] / sqrtf(bn1_v[t] + 1e-5f);
        bias1f[t] = p1_b[t] * inv1 + bn1_b[t] - bn1_m[t] * inv1;
        float inv2 = bn2_g[t] / sqrtf(bn2_v[t] + 1e-5f);
        inv2f[t] = inv2;
        bias2f[t] = dcn_b[t] * inv2 + bn2_b[t] - bn2_m[t] * inv2;
    } else if (blk <= 256) {
        int ci = blk - 1;
        float inv1 = bn1_g[t] / sqrtf(bn1_v[t] + 1e-5f);
        p1_wb[t*256 + ci] = f2bs(p1_w[t*256 + ci] * inv1);   // [o][ci], bn1 folded
    } else if (blk <= 2560) {
        int ck = blk - 257;                             // ck = c*9+tap (original order)
        int c = ck / 9, tap = ck % 9;
        Wbf[t*2304 + tap*256 + c] = f2bs(dcn_w[t*2304 + ck]);  // [o][tap*256+c]
    } else {
        int e = blk - 2561;                             // e = tap*512+ci (new K order)
        if (t < 32) {
            int tap = e >> 9, ci = e & 511;
            float v = off_w[((t < 27) ? t : 0)*4608 + ci*9 + tap];
            Woffb[t*4608 + e] = (t < 27) ? f2bs(v) : (short)0;  // [oc pad32][tap*512+ci]
        }
    }
}

// ---------------- halo zero: Xpad boundary cells (260/b) ----------------
// grid 2080 x 256; each thread zeroes one uint (2 bf16)
__global__ void k_halo(unsigned* __restrict__ Xpad)
{
    int blk = blockIdx.x, t = threadIdx.x;
    int b = blk / 260, i = blk % 260;
    int y, x;
    if (i < 66)       { y = 0;  x = i; }
    else if (i < 132) { y = 65; x = i - 66; }
    else { int j = i - 132; y = 1 + (j >> 1); x = (j & 1) * 65; }
    Xpad[((size_t)(b*66 + y)*66 + x)*256 + t] = 0u;
}

// ---------------- transpose+flip -> Xpad flip half (bf16, channels-last) -----
// grid 2048 x 256  (8 b * 64 h * 4 c-groups)
__global__ void k_featT(const float* __restrict__ feature, short* __restrict__ Xpad)
{
    __shared__ float tile[64][65];
    int bb = blockIdx.x;
    int cg = bb & 3, h = (bb >> 2) & 63, b = bb >> 8;
    int c0 = cg * 64;
    int t = threadIdx.x;
    int lw = t & 63, li = t >> 6;
    #pragma unroll
    for (int j = 0; j < 16; ++j) {
        int cl = j*4 + li;
        tile[cl][63 - lw] = feature[((b*256 + c0 + cl)*64 + h)*64 + lw];
    }
    __syncthreads();
    #pragma unroll
    for (int j = 0; j < 16; ++j) {
        int wl = j*4 + li;
        Xpad[((size_t)(b*66 + h+1)*66 + (wl+1))*512 + c0 + lw] = f2bs(tile[lw][wl]);
    }
}

// ---------------- proj via MFMA: M=256(o) N=32768(pos) K=256(ci) --------------
// grid 512 (2 m-tiles x 256 n-tiles) x 256; writes Xpad proj half
__global__ __launch_bounds__(256) void k_projm(
    short* Xpad, const short* __restrict__ p1_wb, const float* __restrict__ bias1f)
{
    __shared__ short Ash[128*32];
    __shared__ short Bsh[128*32];
    int bid = blockIdx.x;
    int mt = bid & 1, nt = bid >> 1;
    int m0 = mt*128, n0 = nt*128;
    int t = threadIdx.x;
    int lane = t & 63, w = t >> 6;
    int ln = lane & 15, q = lane >> 4;
    int wr = w & 1, wc = w >> 1;
    int ccol = (lane & 3)*8;

    const short* gA1 = p1_wb + (size_t)(m0 + w*16 + (lane>>2))*256 + ccol;
    const short* gA2 = gA1 + 64*256;
    int pos1 = n0 + w*16 + (lane>>2);
    int pos2 = pos1 + 64;
    int b1 = pos1 >> 12, hw1 = pos1 & 4095;
    int b2 = pos2 >> 12, hw2 = pos2 & 4095;
    const short* gB1 = Xpad + ((size_t)(b1*66 + (hw1>>6) + 1)*66 + (64 - (hw1 & 63)))*512 + ccol;
    const short* gB2 = Xpad + ((size_t)(b2*66 + (hw2>>6) + 1)*66 + (64 - (hw2 & 63)))*512 + ccol;
    short* lA = Ash + (w*16)*32;
    short* lB = Bsh + (w*16)*32;

    f32x4 acc[4][4] = {};
    for (int kt = 0; kt < 8; ++kt) {
        gl2lds16(gA1, lA);
        gl2lds16(gA2, lA + 64*32);
        gl2lds16(gB1, lB);
        gl2lds16(gB2, lB + 64*32);
        gA1 += 32; gA2 += 32; gB1 += 32; gB2 += 32;
        __syncthreads();
        short8 af[4], bfr[4];
        #pragma unroll
        for (int i = 0; i < 4; ++i)
            af[i] = *(const short8*)&Ash[(wr*64 + i*16 + ln)*32 + q*8];
        #pragma unroll
        for (int j = 0; j < 4; ++j)
            bfr[j] = *(const short8*)&Bsh[(wc*64 + j*16 + ln)*32 + q*8];
        #pragma unroll
        for (int i = 0; i < 4; ++i)
            #pragma unroll
            for (int j = 0; j < 4; ++j)
                acc[i][j] = __builtin_amdgcn_mfma_f32_16x16x32_bf16(af[i], bfr[j], acc[i][j], 0, 0, 0);
        __syncthreads();
    }
    // epilogue: row=o(q*4+r), col=pos(ln); store bf16 into Xpad[...][256+o]
    #pragma unroll
    for (int i = 0; i < 4; ++i) {
        int ob = m0 + wr*64 + i*16 + q*4;
        #pragma unroll
        for (int j = 0; j < 4; ++j) {
            int pos = n0 + wc*64 + j*16 + ln;
            int b = pos >> 12, hw = pos & 4095;
            size_t xb = ((size_t)(b*66 + (hw>>6) + 1)*66 + (hw & 63) + 1)*512 + 256 + ob;
            short4v st;
            st.x = f2bs(acc[i][j][0] + bias1f[ob]);
            st.y = f2bs(acc[i][j][1] + bias1f[ob+1]);
            st.z = f2bs(acc[i][j][2] + bias1f[ob+2]);
            st.w = f2bs(acc[i][j][3] + bias1f[ob+3]);
            *(short4v*)&Xpad[xb] = st;
        }
    }
}

// ---------------- offset conv via MFMA: M=32(27 oc) N=64(x) K=4608 ------------
// grid 512 ((b,h) rows) x 256; K-chunk 32 within one tap -> shifted Xpad rows
__global__ __launch_bounds__(256) void k_offm(
    const short* __restrict__ Xpad, const short* __restrict__ Woffb,
    const float* __restrict__ off_b, float* __restrict__ offv)
{
    __shared__ short Ash[32*32];
    __shared__ short Bsh[64*32];
    int bid = blockIdx.x;
    int b = bid >> 6, h = bid & 63;
    int t = threadIdx.x;
    int lane = t & 63, w = t >> 6;
    int ln = lane & 15, q = lane >> 4;
    int wr = w & 1, wc = w >> 1;
    int row = w*16 + (lane >> 2);      // staging row (A: oc, B: x-pos)
    int ccol = (lane & 3)*8;
    const short* xb = Xpad + (size_t)b*XPB;

    f32x4 acc[2] = {};
    for (int kc = 0; kc < 144; ++kc) {
        int tap = kc >> 4, c0 = (kc & 15) << 5;
        int dy = tap/3 - 1, dx = tap%3 - 1;
        const short* gB = xb + ((size_t)(h + 1 + dy)*66 + (row + dx + 1))*512 + c0 + ccol;
        gl2lds16(gB, Bsh + (w*16)*32);
        if (w < 2) {
            const short* gA = Woffb + (size_t)row*4608 + kc*32 + ccol;
            gl2lds16(gA, Ash + (w*16)*32);
        }
        __syncthreads();
        short8 af = *(const short8*)&Ash[(wr*16 + ln)*32 + q*8];
        #pragma unroll
        for (int j = 0; j < 2; ++j) {
            short8 bfr = *(const short8*)&Bsh[((wc*2 + j)*16 + ln)*32 + q*8];
            acc[j] = __builtin_amdgcn_mfma_f32_16x16x32_bf16(af, bfr, acc[j], 0, 0, 0);
        }
        __syncthreads();
    }
    #pragma unroll
    for (int j = 0; j < 2; ++j) {
        int x = (wc*2 + j)*16 + ln;
        #pragma unroll
        for (int r = 0; r < 4; ++r) {
            int oc = wr*16 + q*4 + r;
            if (oc < 27)
                offv[((b*27 + oc)*64 + h)*64 + x] = acc[j][r] + off_b[oc];
        }
    }
}

// ---------------- sample: masked bilinear im2col -> G[pos][tap*256+c] bf16 ----
// grid 2048 x 256 (b x h x 4 p-groups); uint (2-channel) vectorized gathers
__global__ void k_sample(const short* __restrict__ Xpad,
                         const float* __restrict__ offv,
                         unsigned* __restrict__ G)     // G as uint pairs
{
    __shared__ int   c_off[144*4];
    __shared__ float c_w[144*4];
    int bb = blockIdx.x;
    int pg = bb & 3, h = (bb >> 2) & 63, b = bb >> 8;
    int p0 = pg * 16;
    int t = threadIdx.x;

    if (t < 144) {
        int p = p0 + t / 9, k = t % 9;
        int base = (b*27)*4096 + h*64 + p;
        float dy = offv[base + k*4096];
        float dx = offv[base + (9+k)*4096];
        float ms = offv[base + (18+k)*4096];
        ms = 1.f / (1.f + expf(-ms));
        float py = (float)h + (float)(k/3 - 1) + dy;
        float px = (float)p + (float)(k%3 - 1) + dx;
        float y0f = floorf(py), x0f = floorf(px);
        float wy = py - y0f, wx = px - x0f;
        int y0 = (int)y0f, x0 = (int)x0f;
        int y1 = y0 + 1, x1 = x0 + 1;
        float vy0 = (y0 >= 0 && y0 < 64) ? 1.f : 0.f;
        float vy1 = (y1 >= 0 && y1 < 64) ? 1.f : 0.f;
        float vx0 = (x0 >= 0 && x0 < 64) ? 1.f : 0.f;
        float vx1 = (x1 >= 0 && x1 < 64) ? 1.f : 0.f;
        int y0c = min(max(y0,0),63), y1c = min(max(y1,0),63);
        int x0c = min(max(x0,0),63), x1c = min(max(x1,0),63);
        // offsets in uint units (c-pair index): cell*512/2 = cell*256
        c_off[t*4+0] = ((y0c+1)*66 + x0c+1)*256;
        c_off[t*4+1] = ((y0c+1)*66 + x1c+1)*256;
        c_off[t*4+2] = ((y1c+1)*66 + x0c+1)*256;
        c_off[t*4+3] = ((y1c+1)*66 + x1c+1)*256;
        c_w[t*4+0] = ms * (1.f-wy)*(1.f-wx) * vy0*vx0;
        c_w[t*4+1] = ms * (1.f-wy)*wx       * vy0*vx1;
        c_w[t*4+2] = ms * wy*(1.f-wx)       * vy1*vx0;
        c_w[t*4+3] = ms * wy*wx             * vy1*vx1;
    }
    __syncthreads();

    int tc = t & 63, tg = t >> 6;                  // tc: c-pair lane, tg: wave
    const unsigned* fT = (const unsigned*)Xpad + (size_t)b*(XPB/2);
    size_t rb = ((size_t)b*4096 + h*64 + p0);
    #pragma unroll
    for (int pi = 0; pi < 4; ++pi) {
        int pl = tg*4 + pi;                        // wave-uniform local p
        size_t grow = (rb + pl)*1152;              // G row in uint units (2304/2)
        #pragma unroll
        for (int k = 0; k < 9; ++k) {
            int e = pl*9 + k;
            const int4   co = *(const int4*)&c_off[e*4];
            const float4 cw = *(const float4*)&c_w[e*4];
            #pragma unroll
            for (int cg = 0; cg < 2; ++cg) {
                int c2 = cg*64 + tc;               // c-pair index 0..127
                unsigned u0 = fT[co.x + c2];
                unsigned u1 = fT[co.y + c2];
                unsigned u2 = fT[co.z + c2];
                unsigned u3 = fT[co.w + c2];
                float glo = cw.x*blo(u0) + cw.y*blo(u1) + cw.z*blo(u2) + cw.w*blo(u3);
                float ghi = cw.x*bhi(u0) + cw.y*bhi(u1) + cw.z*bhi(u2) + cw.w*bhi(u3);
                G[grow + k*128 + c2] = pack2(glo, ghi);
            }
        }
    }
}

// ---------------- dcn GEMM via bf16 MFMA: C[o][pos] + epilogue ----------------
// M=256(o) 2 tiles, N=32768(pos) 256 tiles, K=2304 (72 chunks of 32)
__global__ __launch_bounds__(256) void k_gemm(
    const short* __restrict__ G,      // [32768][2304] bf16
    const short* __restrict__ Wbf,    // [256][2304] bf16
    const short* __restrict__ Xpad,   // residual: proj half
    const float* __restrict__ inv2f, const float* __restrict__ bias2f,
    float* __restrict__ out)
{
    __shared__ short Ash[128*32];
    __shared__ short Bsh[128*32];
    int bid = blockIdx.x;
    int mt = bid & 1, nt = bid >> 1;
    int m0 = mt*128, n0 = nt*128;
    int t = threadIdx.x;
    int lane = t & 63, w = t >> 6;
    int ln = lane & 15, q = lane >> 4;
    int wr = w & 1, wc = w >> 1;

    const short* gA = Wbf + (size_t)(m0 + w*16 + (lane>>2))*2304 + (lane&3)*8;
    const short* gB = G   + (size_t)(n0 + w*16 + (lane>>2))*2304 + (lane&3)*8;
    short* lA = Ash + (w*16)*32;
    short* lB = Bsh + (w*16)*32;

    f32x4 acc[4][4] = {};
    for (int kt = 0; kt < 72; ++kt) {
        gl2lds16(gA,           lA);
        gl2lds16(gA + 64*2304, lA + 64*32);
        gl2lds16(gB,           lB);
        gl2lds16(gB + 64*2304, lB + 64*32);
        gA += 32; gB += 32;
        __syncthreads();
        short8 af[4], bfr[4];
        #pragma unroll
        for (int i = 0; i < 4; ++i)
            af[i] = *(const short8*)&Ash[(wr*64 + i*16 + ln)*32 + q*8];
        #pragma unroll
        for (int j = 0; j < 4; ++j)
            bfr[j] = *(const short8*)&Bsh[(wc*64 + j*16 + ln)*32 + q*8];
        #pragma unroll
        for (int i = 0; i < 4; ++i)
            #pragma unroll
            for (int j = 0; j < 4; ++j)
                acc[i][j] = __builtin_amdgcn_mfma_f32_16x16x32_bf16(af[i], bfr[j], acc[i][j], 0, 0, 0);
        __syncthreads();
    }

    // epilogue: bn2 + residual(from Xpad proj half) + relu
    #pragma unroll
    for (int i = 0; i < 4; ++i) {
        int ob = m0 + wr*64 + i*16 + q*4;
        #pragma unroll
        for (int j = 0; j < 4; ++j) {
            int pos = n0 + wc*64 + j*16 + ln;
            int b = pos >> 12, hw = pos & 4095;
            size_t xb = ((size_t)(b*66 + (hw>>6) + 1)*66 + (hw & 63) + 1)*512 + 256 + ob;
            short4v pr = *(const short4v*)&Xpad[xb];
            #pragma unroll
            for (int r = 0; r < 4; ++r) {
                int o = ob + r;
                size_t idx = ((size_t)(b*256 + o))*4096 + hw;
                float rs = bs2f(((const short*)&pr)[r]);
                float v = rs + acc[i][j][r]*inv2f[o] + bias2f[o];
                out[idx] = v < 0.f ? 0.f : v;   // NaN-propagating relu
            }
        }
    }
}

extern "C" void kernel_launch(void* const* d_in, const int* in_sizes, int n_in,
                              void* d_out, int out_size, void* d_ws, size_t ws_size,
                              hipStream_t stream)
{
    const float* feature = (const float*)d_in[0];
    const float* p1_w  = (const float*)d_in[1];
    const float* p1_b  = (const float*)d_in[2];
    const float* bn1_g = (const float*)d_in[3];
    const float* bn1_b = (const float*)d_in[4];
    const float* bn1_m = (const float*)d_in[5];
    const float* bn1_v = (const float*)d_in[6];
    const float* off_w = (const float*)d_in[7];
    const float* off_b = (const float*)d_in[8];
    const float* dcn_w = (const float*)d_in[9];
    const float* dcn_b = (const float*)d_in[10];
    const float* bn2_g = (const float*)d_in[11];
    const float* bn2_b = (const float*)d_in[12];
    const float* bn2_m = (const float*)d_in[13];
    const float* bn2_v = (const float*)d_in[14];

    // Workspace (float-slot offsets). Total 47,956,736 f = 191.8 MB
    float* ws = (float*)d_ws;
    short* Xpad   = (short*)ws;                 // 17,842,176 sh = 8,921,088 f
    float* offbuf = ws + 8921088;               //    884,736 f
    short* p1_wb  = (short*)(ws + 9805824);     //     65,536 sh = 32,768 f
    short* Woffb  = (short*)(ws + 9838592);     //    147,456 sh = 73,728 f
    short* Wbf    = (short*)(ws + 9912320);     //    589,824 sh = 294,912 f
    float* bias1f = ws + 10207232;              //        256
    float* inv2f  = ws + 10207488;              //        256
    float* bias2f = ws + 10207744;              //        256
    short* G      = (short*)(ws + 10208000);    // 75,497,472 sh = 37,748,736 f

    k_prep<<<7169, 256, 0, stream>>>(p1_w, p1_b, bn1_g, bn1_b, bn1_m, bn1_v,
                                     off_w, dcn_w, dcn_b, bn2_g, bn2_b, bn2_m, bn2_v,
                                     p1_wb, Woffb, Wbf, bias1f, inv2f, bias2f);
    k_halo<<<2080, 256, 0, stream>>>((unsigned*)Xpad);
    k_featT<<<2048, 256, 0, stream>>>(feature, Xpad);
    k_projm<<<512, 256, 0, stream>>>(Xpad, p1_wb, bias1f);
    k_offm<<<512, 256, 0, stream>>>(Xpad, Woffb, off_b, offbuf);
    k_sample<<<2048, 256, 0, stream>>>(Xpad, offbuf, (unsigned*)G);
    k_gemm<<<512, 256, 0, stream>>>(G, Wbf, Xpad, inv2f, bias2f, (float*)d_out);
}